// Round 5
// baseline (3653.709 us; speedup 1.0000x reference)
//
#include <hip/hip_runtime.h>
#include <hip/hip_bf16.h>

// LSTM: B=1024, SEQ=128, H=1024, NCLS=10, IN_DIM=1.
// Per-step launches (kernel-boundary grid sync). fp16 MFMA 16x16x32,
// 128x128 block tile, 2x2 waves of 64x64 (4x4 acc).
// A (h_in): LDS double-buffered BK=64, XOR-swizzled global_load_lds w=16.
// B (weights): register-double-buffered direct global->VGPR fragment loads
//   (no LDS, no swizzle — packed layout makes frags 16 B contiguous).
// fp32 cell state in global, fast exp-based activations.

#define HDIM 1024
#define SEQ 128
#define NCLS 10

using half8   = __attribute__((ext_vector_type(8))) _Float16;
using floatx4 = __attribute__((ext_vector_type(4))) float;

#define GLOBAL_AS const __attribute__((address_space(1))) void*
#define LDS_AS __attribute__((address_space(3))) void*

__device__ __forceinline__ float fast_sig(float x) {
    return __builtin_amdgcn_rcpf(1.f + __expf(-x));
}
__device__ __forceinline__ float fast_tanh(float x) {
    return 1.f - 2.f * __builtin_amdgcn_rcpf(__expf(2.f * x) + 1.f);
}

// ---------------------------------------------------------------------------
// Prepack weights fp32->fp16, gate-interleaved: packed row c of u-slice:
// half=c>>6, gate=(c>>4)&3, ul=c&15 -> unit j = u*32 + half*16 + ul.
// Wave wc then holds all 4 gates of its unit register-locally.
// ---------------------------------------------------------------------------
__global__ void prepack_kernel(const float* __restrict__ wgh,
                               const float* __restrict__ wih,
                               const float* __restrict__ wfh,
                               const float* __restrict__ woh,
                               _Float16* __restrict__ Wp) {
    int p = blockIdx.x;                 // 0..4095
    int u = p >> 7, c = p & 127;
    int half_ = c >> 6, g = (c >> 4) & 3, ul = c & 15;
    int j = u * 32 + half_ * 16 + ul;
    const float* src = (g == 0) ? wgh : (g == 1) ? wih : (g == 2) ? wfh : woh;
    src += (size_t)j * HDIM;
    int k = threadIdx.x * 4;
    float4 v = *(const float4*)(src + k);
    union { _Float16 h[4]; uint2 u2; } cv;
    cv.h[0] = (_Float16)v.x; cv.h[1] = (_Float16)v.y;
    cv.h[2] = (_Float16)v.z; cv.h[3] = (_Float16)v.w;
    *(uint2*)(Wp + (size_t)p * HDIM + k) = cv.u2;
}

// ---------------------------------------------------------------------------
// One LSTM step. 256 WGs x 256 thr (1/CU). Tile 128 batch x 128 gate-cols.
// t==0: GEMM skipped, c treated as zero.
// ---------------------------------------------------------------------------
__global__ __launch_bounds__(256, 1) void lstm_step(
    const _Float16* __restrict__ h_in, _Float16* __restrict__ h_out,
    float* __restrict__ c_state, const _Float16* __restrict__ Wp,
    const float* __restrict__ x, int t,
    const float* __restrict__ wgx, const float* __restrict__ wix,
    const float* __restrict__ wfx, const float* __restrict__ wox,
    const float* __restrict__ bg, const float* __restrict__ bi,
    const float* __restrict__ bf, const float* __restrict__ bo)
{
    __shared__ _Float16 lA[2][128 * 64];   // 2 x 16 KB (A tiles only)

    const int blk = blockIdx.x;
    const int u   = (blk & 7) * 4 + ((blk >> 3) & 3);  // unit-tile, XCD-local
    const int bc  = blk >> 5;
    const int b0  = bc * 128;
    const int tid = threadIdx.x;
    const int wv  = tid >> 6;
    const int l   = tid & 63;
    const int lane15 = l & 15;
    const int quad   = l >> 4;
    const int rf     = lane15 & 7;
    const int wr = wv >> 1, wc = wv & 1;

    // this lane's unit j; epilogue constants
    const int j = u * 32 + wc * 16 + lane15;
    const float wgx_ = wgx[j], wix_ = wix[j], wfx_ = wfx[j], wox_ = wox[j];
    const float bg_ = bg[j], bi_ = bi[j], bf_ = bf[j], bo_ = bo[j];

    // prefetch c-state and x (latency hidden under staging/GEMM)
    float creg[4][4];
    float xr[4][4];
    #pragma unroll
    for (int mt = 0; mt < 4; ++mt) {
        #pragma unroll
        for (int r = 0; r < 4; ++r) {
            const int m = wr * 64 + mt * 16 + quad * 4 + r;
            xr[mt][r] = x[(size_t)(b0 + m) * SEQ + t];
            creg[mt][r] = (t > 0) ? c_state[(size_t)(b0 + m) * HDIM + j] : 0.f;
        }
    }

    // A staging: per wave 4 global_load_lds per tile; 1 instr = 8 rows x 16 B
    int goff[4], ldst[4];
    const int kb = (l & 7) ^ (l >> 3);
    #pragma unroll
    for (int i = 0; i < 4; ++i) {
        int rowb = wv * 32 + i * 8;
        goff[i] = (rowb + (l >> 3)) * HDIM + kb * 8;
        ldst[i] = rowb * 64 + l * 8;
    }

    // B fragment pointers: frag (kc, nt) at bptr[nt] + kt*64 + kc*32
    // (B[n=lane15][k=quad*8+j], 16 B contiguous per lane)
    const _Float16* bptr[4];
    {
        const _Float16* Bbase = Wp + (size_t)u * 128 * HDIM;
        #pragma unroll
        for (int nt = 0; nt < 4; ++nt)
            bptr[nt] = Bbase + (size_t)(wc * 64 + nt * 16 + lane15) * HDIM + quad * 8;
    }

    floatx4 acc[4][4] = {};

    if (t > 0) {
        const _Float16* Abase = h_in + (size_t)b0 * HDIM;

        half8 breg[2][2][4];   // [buf][kc][nt]

        // prologue: stage A(0) into lA[0]; load B(0) into breg[0]
        #pragma unroll
        for (int i = 0; i < 4; ++i)
            __builtin_amdgcn_global_load_lds((GLOBAL_AS)(Abase + goff[i]),
                                             (LDS_AS)(&lA[0][ldst[i]]), 16, 0, 0);
        #pragma unroll
        for (int kc = 0; kc < 2; ++kc)
            #pragma unroll
            for (int nt = 0; nt < 4; ++nt)
                breg[0][kc][nt] = *(const half8*)(bptr[nt] + kc * 32);
        __syncthreads();

        #pragma unroll 2
        for (int kt = 0; kt < 16; ++kt) {
            const int cur = kt & 1;
            if (kt < 15) {
                const int k0 = (kt + 1) * 64;
                #pragma unroll
                for (int i = 0; i < 4; ++i)
                    __builtin_amdgcn_global_load_lds(
                        (GLOBAL_AS)(Abase + goff[i] + k0),
                        (LDS_AS)(&lA[1 - cur][ldst[i]]), 16, 0, 0);
                #pragma unroll
                for (int kc = 0; kc < 2; ++kc)
                    #pragma unroll
                    for (int nt = 0; nt < 4; ++nt)
                        breg[1 - cur][kc][nt] =
                            *(const half8*)(bptr[nt] + k0 + kc * 32);
            }
            const _Float16* bufA = &lA[cur][0];
            #pragma unroll
            for (int kc = 0; kc < 2; ++kc) {
                const int slot = ((kc * 4 + quad) ^ rf) * 8;
                half8 afr[4];
                #pragma unroll
                for (int mt = 0; mt < 4; ++mt)
                    afr[mt] = *(const half8*)(bufA + (wr * 64 + mt * 16 + lane15) * 64 + slot);
                #pragma unroll
                for (int mt = 0; mt < 4; ++mt)
                    #pragma unroll
                    for (int nt = 0; nt < 4; ++nt)
                        acc[mt][nt] = __builtin_amdgcn_mfma_f32_16x16x32_f16(
                            afr[mt], breg[cur][kc][nt], acc[mt][nt], 0, 0, 0);
            }
            __syncthreads();
        }
    }

    // fused LSTM cell epilogue: lane holds all 4 gates of (batch m, unit j)
    #pragma unroll
    for (int mt = 0; mt < 4; ++mt) {
        #pragma unroll
        for (int r = 0; r < 4; ++r) {
            const int m = wr * 64 + mt * 16 + quad * 4 + r;
            const float xt = xr[mt][r];
            const size_t idx = (size_t)(b0 + m) * HDIM + j;
            float pg = acc[mt][0][r] + xt * wgx_ + bg_;
            float pi = acc[mt][1][r] + xt * wix_ + bi_;
            float pf = acc[mt][2][r] + xt * wfx_ + bf_;
            float po = acc[mt][3][r] + xt * wox_ + bo_;
            float g  = fast_tanh(pg);
            float ii = fast_sig(pi);
            float ff = fast_sig(pf);
            float oo = fast_sig(po);
            float cn = g * ii + creg[mt][r] * ff;
            c_state[idx] = cn;
            h_out[idx] = (_Float16)(fast_tanh(cn) * oo);
        }
    }
}

// ---------------------------------------------------------------------------
// logits = h_last @ w_ph^T + bias_p. One wave per batch row.
// ---------------------------------------------------------------------------
__global__ void logits_kernel(const _Float16* __restrict__ h,
                              const float* __restrict__ wph,
                              const float* __restrict__ bp,
                              float* __restrict__ out) {
    const int w = (blockIdx.x * blockDim.x + threadIdx.x) >> 6; // 0..1023
    const int l = threadIdx.x & 63;
    float accv[NCLS];
    #pragma unroll
    for (int c = 0; c < NCLS; ++c) accv[c] = 0.f;
    for (int k = l; k < HDIM; k += 64) {
        float hv = (float)h[(size_t)w * HDIM + k];
        #pragma unroll
        for (int c = 0; c < NCLS; ++c)
            accv[c] += hv * wph[c * HDIM + k];
    }
    #pragma unroll
    for (int c = 0; c < NCLS; ++c) {
        float v = accv[c];
        #pragma unroll
        for (int off = 32; off > 0; off >>= 1)
            v += __shfl_down(v, off, 64);
        if (l == 0) out[w * NCLS + c] = v + bp[c];
    }
}

extern "C" void kernel_launch(void* const* d_in, const int* in_sizes, int n_in,
                              void* d_out, int out_size, void* d_ws, size_t ws_size,
                              hipStream_t stream) {
    const float* x   = (const float*)d_in[0];
    const float* wgx = (const float*)d_in[1];
    const float* wgh = (const float*)d_in[2];
    const float* wix = (const float*)d_in[3];
    const float* wih = (const float*)d_in[4];
    const float* wfx = (const float*)d_in[5];
    const float* wfh = (const float*)d_in[6];
    const float* wox = (const float*)d_in[7];
    const float* woh = (const float*)d_in[8];
    const float* wph = (const float*)d_in[9];
    const float* bg  = (const float*)d_in[10];
    const float* bi  = (const float*)d_in[11];
    const float* bf  = (const float*)d_in[12];
    const float* bo  = (const float*)d_in[13];
    const float* bp  = (const float*)d_in[14];
    float* out = (float*)d_out;

    char* ws = (char*)d_ws;
    _Float16* Wp    = (_Float16*)(ws);               // 0..8 MB
    _Float16* hbuf0 = (_Float16*)(ws + (8u << 20));  // 8..10 MB
    _Float16* hbuf1 = (_Float16*)(ws + (10u << 20)); // 10..12 MB
    float*    cst   = (float*)(ws + (12u << 20));    // 12..16 MB

    prepack_kernel<<<4096, 256, 0, stream>>>(wgh, wih, wfh, woh, Wp);

    for (int t = 0; t < SEQ; ++t) {
        _Float16* hin  = (t & 1) ? hbuf0 : hbuf1;   // t=0 value unread
        _Float16* hout = (t & 1) ? hbuf1 : hbuf0;
        lstm_step<<<256, 256, 0, stream>>>(hin, hout, cst, Wp, x, t,
                                           wgx, wix, wfx, wox, bg, bi, bf, bo);
    }
    logits_kernel<<<256, 256, 0, stream>>>(hbuf1, wph, bp, out);  // t=127 -> hbuf1
}

// Round 7
// 2305.952 us; speedup vs baseline: 1.5845x; 1.5845x over previous
//
#include <hip/hip_runtime.h>
#include <hip/hip_bf16.h>

// LSTM: B=1024, SEQ=128, H=1024, NCLS=10, IN_DIM=1.
// Per-step launches. fp16 MFMA 16x16x32, 128x128 block tile, 2x2 waves of
// 64x64 (4x4 acc). A (h_in): LDS double-buffered BK=128 (64 KiB), XOR-swizzle,
// staged via global_load_lds w=16 with 4-rows-per-instruction layout (HW dest
// is wave-uniform base + lane*16 — layout must match lane placement exactly).
// B (weights): NO LDS — prepacked FRAGMENT-MAJOR, each B fragment is one
// coalesced 1KB global_load_dwordx4 (base + lane*16), register-pipelined.
// fp32 cell state, fast exp activations.

#define HDIM 1024
#define SEQ 128
#define NCLS 10

using half8   = __attribute__((ext_vector_type(8))) _Float16;
using floatx4 = __attribute__((ext_vector_type(4))) float;

#define GLOBAL_AS const __attribute__((address_space(1))) void*
#define LDS_AS __attribute__((address_space(3))) void*

__device__ __forceinline__ float fast_sig(float x) {
    return __builtin_amdgcn_rcpf(1.f + __expf(-x));
}
__device__ __forceinline__ float fast_tanh(float x) {
    return 1.f - 2.f * __builtin_amdgcn_rcpf(__expf(2.f * x) + 1.f);
}

// ---------------------------------------------------------------------------
// Prepack fp32->fp16, FRAGMENT-MAJOR chunks of 1 KB:
// chunk = ((u*8 + kt)*4 + kc)*8 + ng   (u<32, kt<8, kc<4, ng<8)
// within chunk, half index = quad*128 + nl*8 + i  (= lane*8 + i)
// logical col c = ng*16 + nl (gate=(c>>4)&3, j=u*32+(c>>6)*16+(c&15)),
// k = kt*128 + kc*32 + quad*8 + i.
// Wave reads a fragment as chunk_base + lane*16 — fully coalesced.
// ---------------------------------------------------------------------------
__global__ void prepack_kernel(const float* __restrict__ wgh,
                               const float* __restrict__ wih,
                               const float* __restrict__ wfh,
                               const float* __restrict__ woh,
                               _Float16* __restrict__ Wp) {
    const int chunk = blockIdx.x;        // 0..8191
    const int l = threadIdx.x;           // 0..63
    const int ng = chunk & 7;
    const int kc = (chunk >> 3) & 3;
    const int kt = (chunk >> 5) & 7;
    const int u  = chunk >> 8;
    const int quad = l >> 4, nl = l & 15;
    const int c = ng * 16 + nl;
    const int gate = (c >> 4) & 3;
    const int j = u * 32 + (c >> 6) * 16 + (c & 15);
    const int k0 = kt * 128 + kc * 32 + quad * 8;
    const float* src = (gate == 0) ? wgh : (gate == 1) ? wih
                     : (gate == 2) ? wfh : woh;
    src += (size_t)j * HDIM + k0;
    float4 v0 = *(const float4*)(src);
    float4 v1 = *(const float4*)(src + 4);
    union { _Float16 h[8]; uint4 u4; } cv;
    cv.h[0] = (_Float16)v0.x; cv.h[1] = (_Float16)v0.y;
    cv.h[2] = (_Float16)v0.z; cv.h[3] = (_Float16)v0.w;
    cv.h[4] = (_Float16)v1.x; cv.h[5] = (_Float16)v1.y;
    cv.h[6] = (_Float16)v1.z; cv.h[7] = (_Float16)v1.w;
    *(uint4*)(Wp + (size_t)chunk * 512 + l * 8) = cv.u4;
}

// ---------------------------------------------------------------------------
// One LSTM step. 256 WGs x 256 thr (1/CU). Tile 128 batch x 128 gate-cols.
// t==0: GEMM skipped, c treated as zero.
// ---------------------------------------------------------------------------
__global__ __launch_bounds__(256, 1) void lstm_step(
    const _Float16* __restrict__ h_in, _Float16* __restrict__ h_out,
    float* __restrict__ c_state, const _Float16* __restrict__ Wp,
    const float* __restrict__ x, int t,
    const float* __restrict__ wgx, const float* __restrict__ wix,
    const float* __restrict__ wfx, const float* __restrict__ wox,
    const float* __restrict__ bg, const float* __restrict__ bi,
    const float* __restrict__ bf, const float* __restrict__ bo)
{
    __shared__ _Float16 lA[2][128 * 128];   // 2 x 32 KB (A tiles, BK=128)

    const int blk = blockIdx.x;
    const int u   = (blk & 7) * 4 + ((blk >> 3) & 3);  // unit-tile, XCD-local
    const int bc  = blk >> 5;
    const int b0  = bc * 128;
    const int tid = threadIdx.x;
    const int wv  = tid >> 6;
    const int l   = tid & 63;
    const int lane15 = l & 15;
    const int quad   = l >> 4;
    const int rf     = lane15 & 7;
    const int wr = wv >> 1, wc = wv & 1;

    // this lane's unit j; epilogue constants
    const int j = u * 32 + wc * 16 + lane15;
    const float wgx_ = wgx[j], wix_ = wix[j], wfx_ = wfx[j], wox_ = wox[j];
    const float bg_ = bg[j], bi_ = bi[j], bf_ = bf[j], bo_ = bo[j];

    // prefetch c-state and x
    float creg[4][4];
    float xr[4][4];
    #pragma unroll
    for (int mt = 0; mt < 4; ++mt) {
        #pragma unroll
        for (int r = 0; r < 4; ++r) {
            const int m = wr * 64 + mt * 16 + quad * 4 + r;
            xr[mt][r] = x[(size_t)(b0 + m) * SEQ + t];
            creg[mt][r] = (t > 0) ? c_state[(size_t)(b0 + m) * HDIM + j] : 0.f;
        }
    }

    // A staging (BK=128): 8 instrs/wave, each = 4 rows x 16 slots.
    // lane l: row-in-instr = l>>4, slot = l&15; HW dest = base + l*16 B
    // lands at LDS (row*128 + slot*8) halves exactly (contiguous, no overlap).
    // Global kb fetched = slot ^ (row&7): LDS slot s of row r holds kb = s^(r&7).
    // instr i covers rows wv*32 + i*4 .. +3; (i*4 + l>>4)&7 = (i&1)*4 + (l>>4).
    const int rowA = l >> 4;
    const int kbE  = lane15 ^ rowA;          // swizzled kb, even i
    const int gE   = rowA * HDIM + kbE * 8;
    const int gO   = rowA * HDIM + (kbE ^ 4) * 8;   // odd i
    const int lbase = wv * 4096 + l * 8;     // lA halves: wv*32 rows * 128

    // B fragment pointer: frag(kt,kc,nt) at Bl + ((kt*4+kc)*8+nt)*512 halves
    const _Float16* Bl = Wp + ((size_t)u * 256 + wc * 4) * 512 + l * 8;

    floatx4 acc[4][4] = {};

    if (t > 0) {
        const _Float16* Abase = h_in + (size_t)b0 * HDIM + (size_t)wv * 32 * HDIM;

        half8 bp0[2][4], bp1[2][4];   // kc-pair register pipeline

        // prologue: stage A(kt=0) into lA[0]; load B kc{0,1} of kt0
        #pragma unroll
        for (int i = 0; i < 8; ++i) {
            const int go = i * 4 * HDIM + ((i & 1) ? gO : gE);
            __builtin_amdgcn_global_load_lds((GLOBAL_AS)(Abase + go),
                                             (LDS_AS)(&lA[0][lbase + i * 512]), 16, 0, 0);
        }
        #pragma unroll
        for (int kc = 0; kc < 2; ++kc)
            #pragma unroll
            for (int nt = 0; nt < 4; ++nt)
                bp0[kc][nt] = *(const half8*)(Bl + ((0 * 4 + kc) * 8 + nt) * 512);
        __syncthreads();

        #pragma unroll 2
        for (int kt = 0; kt < 8; ++kt) {
            const int cur = kt & 1;
            // issue B kc{2,3} of this kt
            #pragma unroll
            for (int kc = 0; kc < 2; ++kc)
                #pragma unroll
                for (int nt = 0; nt < 4; ++nt)
                    bp1[kc][nt] = *(const half8*)(Bl + ((kt * 4 + 2 + kc) * 8 + nt) * 512);
            // stage A(kt+1) into the other buffer
            if (kt < 7) {
                const int k0 = (kt + 1) * 128;
                #pragma unroll
                for (int i = 0; i < 8; ++i) {
                    const int go = i * 4 * HDIM + ((i & 1) ? gO : gE);
                    __builtin_amdgcn_global_load_lds(
                        (GLOBAL_AS)(Abase + go + k0),
                        (LDS_AS)(&lA[1 - cur][lbase + i * 512]), 16, 0, 0);
                }
            }
            const _Float16* bufA = &lA[cur][0];
            // compute kc 0,1 with bp0
            #pragma unroll
            for (int kc = 0; kc < 2; ++kc) {
                const int slot = ((kc * 4 + quad) ^ rf) * 8;
                half8 afr[4];
                #pragma unroll
                for (int mt = 0; mt < 4; ++mt)
                    afr[mt] = *(const half8*)(bufA + (wr * 64 + mt * 16 + lane15) * 128 + slot);
                #pragma unroll
                for (int mt = 0; mt < 4; ++mt)
                    #pragma unroll
                    for (int nt = 0; nt < 4; ++nt)
                        acc[mt][nt] = __builtin_amdgcn_mfma_f32_16x16x32_f16(
                            afr[mt], bp0[kc][nt], acc[mt][nt], 0, 0, 0);
            }
            // issue B kc{0,1} of kt+1
            if (kt < 7) {
                #pragma unroll
                for (int kc = 0; kc < 2; ++kc)
                    #pragma unroll
                    for (int nt = 0; nt < 4; ++nt)
                        bp0[kc][nt] = *(const half8*)(Bl + (((kt + 1) * 4 + kc) * 8 + nt) * 512);
            }
            // compute kc 2,3 with bp1
            #pragma unroll
            for (int kc = 0; kc < 2; ++kc) {
                const int slot = (((kc + 2) * 4 + quad) ^ rf) * 8;
                half8 afr[4];
                #pragma unroll
                for (int mt = 0; mt < 4; ++mt)
                    afr[mt] = *(const half8*)(bufA + (wr * 64 + mt * 16 + lane15) * 128 + slot);
                #pragma unroll
                for (int mt = 0; mt < 4; ++mt)
                    #pragma unroll
                    for (int nt = 0; nt < 4; ++nt)
                        acc[mt][nt] = __builtin_amdgcn_mfma_f32_16x16x32_f16(
                            afr[mt], bp1[kc][nt], acc[mt][nt], 0, 0, 0);
            }
            __syncthreads();
        }
    }

    // fused LSTM cell epilogue: lane holds all 4 gates of (batch m, unit j)
    #pragma unroll
    for (int mt = 0; mt < 4; ++mt) {
        #pragma unroll
        for (int r = 0; r < 4; ++r) {
            const int m = wr * 64 + mt * 16 + quad * 4 + r;
            const float xt = xr[mt][r];
            const size_t idx = (size_t)(b0 + m) * HDIM + j;
            float pg = acc[mt][0][r] + xt * wgx_ + bg_;
            float pi = acc[mt][1][r] + xt * wix_ + bi_;
            float pf = acc[mt][2][r] + xt * wfx_ + bf_;
            float po = acc[mt][3][r] + xt * wox_ + bo_;
            float g  = fast_tanh(pg);
            float ii = fast_sig(pi);
            float ff = fast_sig(pf);
            float oo = fast_sig(po);
            float cn = g * ii + creg[mt][r] * ff;
            c_state[idx] = cn;
            h_out[idx] = (_Float16)(fast_tanh(cn) * oo);
        }
    }
}

// ---------------------------------------------------------------------------
// logits = h_last @ w_ph^T + bias_p. One wave per batch row.
// ---------------------------------------------------------------------------
__global__ void logits_kernel(const _Float16* __restrict__ h,
                              const float* __restrict__ wph,
                              const float* __restrict__ bp,
                              float* __restrict__ out) {
    const int w = (blockIdx.x * blockDim.x + threadIdx.x) >> 6; // 0..1023
    const int l = threadIdx.x & 63;
    float accv[NCLS];
    #pragma unroll
    for (int c = 0; c < NCLS; ++c) accv[c] = 0.f;
    for (int k = l; k < HDIM; k += 64) {
        float hv = (float)h[(size_t)w * HDIM + k];
        #pragma unroll
        for (int c = 0; c < NCLS; ++c)
            accv[c] += hv * wph[c * HDIM + k];
    }
    #pragma unroll
    for (int c = 0; c < NCLS; ++c) {
        float v = accv[c];
        #pragma unroll
        for (int off = 32; off > 0; off >>= 1)
            v += __shfl_down(v, off, 64);
        if (l == 0) out[w * NCLS + c] = v + bp[c];
    }
}

extern "C" void kernel_launch(void* const* d_in, const int* in_sizes, int n_in,
                              void* d_out, int out_size, void* d_ws, size_t ws_size,
                              hipStream_t stream) {
    const float* x   = (const float*)d_in[0];
    const float* wgx = (const float*)d_in[1];
    const float* wgh = (const float*)d_in[2];
    const float* wix = (const float*)d_in[3];
    const float* wih = (const float*)d_in[4];
    const float* wfx = (const float*)d_in[5];
    const float* wfh = (const float*)d_in[6];
    const float* wox = (const float*)d_in[7];
    const float* woh = (const float*)d_in[8];
    const float* wph = (const float*)d_in[9];
    const float* bg  = (const float*)d_in[10];
    const float* bi  = (const float*)d_in[11];
    const float* bf  = (const float*)d_in[12];
    const float* bo  = (const float*)d_in[13];
    const float* bp  = (const float*)d_in[14];
    float* out = (float*)d_out;

    char* ws = (char*)d_ws;
    _Float16* Wp    = (_Float16*)(ws);               // 0..8 MB (8192 x 1KB)
    _Float16* hbuf0 = (_Float16*)(ws + (8u << 20));  // 8..10 MB
    _Float16* hbuf1 = (_Float16*)(ws + (10u << 20)); // 10..12 MB
    float*    cst   = (float*)(ws + (12u << 20));    // 12..16 MB

    prepack_kernel<<<8192, 64, 0, stream>>>(wgh, wih, wfh, woh, Wp);

    for (int t = 0; t < SEQ; ++t) {
        _Float16* hin  = (t & 1) ? hbuf0 : hbuf1;   // t=0 value unread
        _Float16* hout = (t & 1) ? hbuf1 : hbuf0;
        lstm_step<<<256, 256, 0, stream>>>(hin, hout, cst, Wp, x, t,
                                           wgx, wix, wfx, wox, bg, bi, bf, bo);
    }
    logits_kernel<<<256, 256, 0, stream>>>(hbuf1, wph, bp, out);  // t=127 -> hbuf1
}